// Round 8
// baseline (61.414 us; speedup 1.0000x reference)
//
#include <hip/hip_runtime.h>

// CorrelationAlign: out[b, a*63+c, i, j] = in[b, (a+i-31)*32 + (c+j-31), i, j]
//   valid iff 0 <= a+i-31 < 32 and 0 <= c+j-31 < 32, else 0.  b=16, h=w=32.
//
// R7: retest of store contiguity WITHOUT R5's occupancy confound.
// Block = 512 threads = 8 waves, one (b, a, i-group-of-8). Wave w privately
// loads tile i=i0+w (32x32, 4x 1KB coalesced instrs) into its LDS slice;
// one barrier; store phase: wave-instr = 64 lanes x 16B = 1KB CONTIGUOUS
// (vs R1's 8x128B comb @ 4KB stride). Lane role (isb, js, pv) fixed across
// the c-loop -> tiny inner VALU. LDS 33.8KB -> 4 blocks/CU x 512 thr =
// 32 waves/CU (FULL occupancy, unlike R5's 16).
// Banks: per-tile stride 1057, row stride 33 -> store-read bank =
// ((lane>>3)+8*(lane&7)+2k+c-31) mod 32, lane-map bijective on 0..63 ->
// exactly 2-way aliasing (free, m136).

#define TSTR 1057   // per-i-subtile LDS stride (floats)

__global__ __launch_bounds__(512) void CorrelationAlign_kernel(
    const float* __restrict__ in, float* __restrict__ out) {
  __shared__ float lds[8 * TSTR];   // 33,824 B

  const int bid = blockIdx.x;       // ((b*63 + a) * 4 + g)
  const int g  = bid & 3;
  const int ba = bid >> 2;
  const int a  = ba % 63;
  const int b  = ba / 63;
  const int i0 = g * 8;
  const int t  = threadIdx.x;
  const int w    = t >> 6;          // wave 0..7
  const int lane = t & 63;

  float* outbase = out + (size_t)(b * 3969 + a * 63) * 1024 + i0 * 32;
  const int plo = a + i0 - 31;      // p for isb = 0

  if (plo <= 31 && plo + 7 >= 0) {  // block-uniform: some tile valid
    // ---- load: wave w owns tile w (wave-uniform validity) ----
    const int p = plo + w;
    if ((unsigned)p < 32u) {
      const float* inbase =
          in + (size_t)(b * 1024 + p * 32) * 1024 + (i0 + w) * 32;
      const int q0 = lane >> 3;           // 0..7
      const int j0 = (lane & 7) * 4;      // 0..28
      float* slice = &lds[w * TSTR];
#pragma unroll
      for (int r = 0; r < 4; ++r) {
        const int q = r * 8 + q0;
        const float4 v =
            *reinterpret_cast<const float4*>(inbase + (size_t)q * 1024 + j0);
        float* dst = &slice[q * 33 + j0];
        dst[0] = v.x; dst[1] = v.y; dst[2] = v.z; dst[3] = v.w;
      }
    }
    __syncthreads();

    // ---- store: per-thread role fixed; wave-instr = 1KB contiguous ----
    const int isb = lane >> 3;            // i sub-index 0..7
    const int js  = (lane & 7) * 4;       // j0 within i's 32 floats
    const bool pv = (unsigned)(plo + isb) < 32u;
    const float* slice = &lds[isb * TSTR];
    for (int c = w; c < 63; c += 8) {     // wave w: c = w, w+8, ...
      float4 v;
      float* vp = reinterpret_cast<float*>(&v);
#pragma unroll
      for (int k = 0; k < 4; ++k) {
        const int j  = js + k;
        const int q  = c + j - 31;
        const int qc = min(max(q, 0), 31);
        const float x = slice[qc * 33 + j];   // garbage ok if !pv
        vp[k] = (pv && (unsigned)q < 32u) ? x : 0.0f;
      }
      *reinterpret_cast<float4*>(outbase + (size_t)c * 1024 + lane * 4) = v;
    }
  } else {
    // ---- whole i-group invalid: zero-fill, 1KB contiguous per instr ----
    const float4 z = make_float4(0.f, 0.f, 0.f, 0.f);
    for (int c = w; c < 63; c += 8)
      *reinterpret_cast<float4*>(outbase + (size_t)c * 1024 + lane * 4) = z;
  }
}

extern "C" void kernel_launch(void* const* d_in, const int* in_sizes, int n_in,
                              void* d_out, int out_size, void* d_ws,
                              size_t ws_size, hipStream_t stream) {
  (void)in_sizes; (void)n_in; (void)out_size; (void)d_ws; (void)ws_size;
  const float* in = (const float*)d_in[0];
  float* out = (float*)d_out;
  const int grid = 16 * 63 * 4;   // one block per (b, a, i-group-of-8)
  CorrelationAlign_kernel<<<grid, 512, 0, stream>>>(in, out);
}